// Round 7
// baseline (4412.824 us; speedup 1.0000x reference)
//
#include <hip/hip_runtime.h>
#include <hip/hip_bf16.h>

using bf16 = __hip_bfloat16;

#define EDGES 25000
#define NNODES 5000
#define EPB 4
#define NBLK (EDGES / EPB)

__device__ __forceinline__ float sigmf(float x) { return 1.0f / (1.0f + expf(-x)); }

template<bool BF>
__device__ __forceinline__ float LD1(const void* p, size_t i) {
    if (BF) return __bfloat162float(((const bf16*)p)[i]);
    else    return ((const float*)p)[i];
}

template<bool BF>
__device__ __forceinline__ float4 LD4(const void* p, size_t i) {
    if (BF) {
        ushort4 u = *reinterpret_cast<const ushort4*>((const bf16*)p + i);
        float4 r;
        r.x = __uint_as_float((unsigned)u.x << 16);
        r.y = __uint_as_float((unsigned)u.y << 16);
        r.z = __uint_as_float((unsigned)u.z << 16);
        r.w = __uint_as_float((unsigned)u.w << 16);
        return r;
    } else {
        return *reinterpret_cast<const float4*>((const float*)p + i);
    }
}

__device__ __forceinline__ void fma4(float4& a, float s, const float4& w) {
    a.x += s * w.x; a.y += s * w.y; a.z += s * w.z; a.w += s * w.w;
}

__device__ __forceinline__ void silu4(float4& a) {
    a.x *= sigmf(a.x); a.y *= sigmf(a.y); a.z *= sigmf(a.z); a.w *= sigmf(a.w);
}

// monotone float<->uint encoding for atomicMax on floats
__device__ __forceinline__ unsigned encF(float f) {
    unsigned b = __float_as_uint(f);
    return (b & 0x80000000u) ? ~b : (b | 0x80000000u);
}
__device__ __forceinline__ float decF(unsigned e) {
    unsigned b = (e & 0x80000000u) ? (e ^ 0x80000000u) : ~e;
    return __uint_as_float(b);
}
#define ENC_NEGINF 0x007FFFFFu

// ---- cross-batch double-buffered weight streaming (2-stage SW pipeline) ----
// Batch k+1's 4 loads are issued BEFORE batch k's FMAs, so 4 loads are always
// in flight during compute (r6 post-mortem: STREAM4 waited full latency/batch).
#define PLOAD4(WD, Wptr, LDW, j0, ii) \
    WD##0 = LD4<BF>(Wptr, (size_t)(ii + 0) * (LDW) + (j0)); \
    WD##1 = LD4<BF>(Wptr, (size_t)(ii + 1) * (LDW) + (j0)); \
    WD##2 = LD4<BF>(Wptr, (size_t)(ii + 2) * (LDW) + (j0)); \
    WD##3 = LD4<BF>(Wptr, (size_t)(ii + 3) * (LDW) + (j0));

#define PFMA_1(WD, ABASE, ii, NACC) \
    _Pragma("unroll") \
    for (int e = 0; e < NACC; e++) { \
        float4 a0 = *(const float4*)((ABASE) + (ii)); \
        fma4(acc[e], a0.x, WD##0); fma4(acc[e], a0.y, WD##1); \
        fma4(acc[e], a0.z, WD##2); fma4(acc[e], a0.w, WD##3); \
    }

// KLEN must be a multiple of 8. acc[NACC] must be live.
#define PSTREAM_1(Wptr, LDW, j0, ABASE, KBASE, KLEN, NACC) \
    { \
        float4 wA0, wA1, wA2, wA3, wB0, wB1, wB2, wB3; \
        int i = (KBASE); \
        const int iend = (KBASE) + (KLEN); \
        PLOAD4(wA, Wptr, LDW, j0, i) \
        for (; i + 8 < iend; i += 8) { \
            PLOAD4(wB, Wptr, LDW, j0, (i + 4)) \
            PFMA_1(wA, ABASE, i, NACC) \
            PLOAD4(wA, Wptr, LDW, j0, (i + 8)) \
            PFMA_1(wB, ABASE, (i + 4), NACC) \
        } \
        PLOAD4(wB, Wptr, LDW, j0, (i + 4)) \
        PFMA_1(wA, ABASE, i, NACC) \
        PFMA_1(wB, ABASE, (i + 4), NACC) \
    }

#define PFMA_2(WD, ABASEA, ABASEB, ii) \
    _Pragma("unroll") \
    for (int e = 0; e < EPB; e++) { \
        float4 a0 = *(const float4*)((ABASEA) + (ii)); \
        float4 b0 = *(const float4*)((ABASEB) + (ii)); \
        fma4(ra[e], a0.x, WD##0); fma4(ra[e], a0.y, WD##1); \
        fma4(ra[e], a0.z, WD##2); fma4(ra[e], a0.w, WD##3); \
        fma4(rb[e], b0.x, WD##0); fma4(rb[e], b0.y, WD##1); \
        fma4(rb[e], b0.z, WD##2); fma4(rb[e], b0.w, WD##3); \
    }

// two-row variant into ra[e], rb[e]; KLEN multiple of 8, KBASE = 0
#define PSTREAM_2(Wptr, LDW, j0, ABASEA, ABASEB, KLEN) \
    { \
        float4 wA0, wA1, wA2, wA3, wB0, wB1, wB2, wB3; \
        int i = 0; \
        const int iend = (KLEN); \
        PLOAD4(wA, Wptr, LDW, j0, i) \
        for (; i + 8 < iend; i += 8) { \
            PLOAD4(wB, Wptr, LDW, j0, (i + 4)) \
            PFMA_2(wA, ABASEA, ABASEB, i) \
            PLOAD4(wA, Wptr, LDW, j0, (i + 8)) \
            PFMA_2(wB, ABASEA, ABASEB, (i + 4)) \
        } \
        PLOAD4(wB, Wptr, LDW, j0, (i + 4)) \
        PFMA_2(wA, ABASEA, ABASEB, i) \
        PFMA_2(wB, ABASEA, ABASEB, (i + 4)) \
    }

// ---------------- dtype detector ----------------
__global__ void k_detect(const void* edge_dist, int* flag) {
    if (threadIdx.x == 0 && blockIdx.x == 0) {
        const bf16* p = (const bf16*)edge_dist;
        int ok = 1;
        for (int i = 0; i < 256; i++) {
            float v = __bfloat162float(p[i]);
            if (!(v >= 0.0f && v <= 1.0f)) { ok = 0; break; }
        }
        *flag = ok;
    }
}

// ---------------- fill ----------------
__global__ void k_fill(float* accb, float* nden, unsigned* nmax) {
    int tid = blockIdx.x * 256 + threadIdx.x;
    if (tid < NNODES * 1600) accb[tid] = 0.0f;
    if (tid < NNODES * 8) { nden[tid] = 0.0f; nmax[tid] = ENC_NEGINF; }
}

// ---------------- alpha prepass: EPB=4, shared weights ----------------
template<bool BF>
__global__ __launch_bounds__(256, 3) void k_alpha(
    const void* __restrict__ node_feats, const void* __restrict__ edge_dist,
    const void* __restrict__ wigner, const void* __restrict__ emb_s,
    const void* __restrict__ emb_r,
    const void* __restrict__ rw1, const void* __restrict__ rb1,
    const void* __restrict__ rl1s, const void* __restrict__ rl1b,
    const void* __restrict__ rw2, const void* __restrict__ rb2,
    const void* __restrict__ rl2s, const void* __restrict__ rl2b,
    const void* __restrict__ rw3, const void* __restrict__ rb3,
    const void* __restrict__ c1w0, const void* __restrict__ c1b0,
    const void* __restrict__ an_s, const void* __restrict__ an_b,
    const void* __restrict__ adot,
    const int* __restrict__ species, const int* __restrict__ senders,
    const int* __restrict__ receivers, const int* __restrict__ dtf,
    float* __restrict__ alpha_out, unsigned* __restrict__ nmax)
{
    if ((*dtf != 0) != BF) return;
    __shared__ __align__(16) float sm[12160];
    float* XE   = sm;
    float* T1   = sm + 768;
    float* H1   = sm + 1024;
    float* T2   = sm + 1280;
    float* H2   = sm + 1536;
    float* rad0 = sm + 1792;
    float* x0   = sm + 4352;
    float* R    = sm + 6912;
    float* extraA = sm + 11136;

    const int t = threadIdx.x;
    const int e0 = blockIdx.x * EPB;
    const int eg = t >> 6, tt = t & 63;

    {
        int ee = e0 + eg;
        XE[eg * 192 + tt]       = LD1<BF>(edge_dist, (size_t)ee * 64 + tt);
        XE[eg * 192 + 64 + tt]  = LD1<BF>(emb_s, (size_t)species[senders[ee]] * 64 + tt);
        XE[eg * 192 + 128 + tt] = LD1<BF>(emb_r, (size_t)species[receivers[ee]] * 64 + tt);
    }
    __syncthreads();
    {
        float a = LD1<BF>(rb1, tt);
        #pragma unroll 4
        for (int k = 0; k < 192; k++) a += XE[eg * 192 + k] * LD1<BF>(rw1, k * 64 + tt);
        T1[eg * 64 + tt] = a;
    }
    __syncthreads();
    {
        float mu = 0.f;
        for (int k = 0; k < 64; k++) mu += T1[eg * 64 + k];
        mu *= (1.f / 64.f);
        float var = 0.f;
        for (int k = 0; k < 64; k++) { float d = T1[eg * 64 + k] - mu; var += d * d; }
        float xn = (T1[eg * 64 + tt] - mu) * rsqrtf(var * (1.f / 64.f) + 1e-6f) * LD1<BF>(rl1s, tt) + LD1<BF>(rl1b, tt);
        H1[eg * 64 + tt] = xn * sigmf(xn);
    }
    __syncthreads();
    {
        float a = LD1<BF>(rb2, tt);
        #pragma unroll 4
        for (int k = 0; k < 64; k++) a += H1[eg * 64 + k] * LD1<BF>(rw2, k * 64 + tt);
        T2[eg * 64 + tt] = a;
    }
    __syncthreads();
    {
        float mu = 0.f;
        for (int k = 0; k < 64; k++) mu += T2[eg * 64 + k];
        mu *= (1.f / 64.f);
        float var = 0.f;
        for (int k = 0; k < 64; k++) { float d = T2[eg * 64 + k] - mu; var += d * d; }
        float xn = (T2[eg * 64 + tt] - mu) * rsqrtf(var * (1.f / 64.f) + 1e-6f) * LD1<BF>(rl2s, tt) + LD1<BF>(rl2b, tt);
        H2[eg * 64 + tt] = xn * sigmf(xn);
    }
    __syncthreads();
    if (t < 160) {
        int j0 = t * 4;
        float4 acc[EPB];
        float4 bv = LD4<BF>(rb3, j0);
        #pragma unroll
        for (int e = 0; e < EPB; e++) acc[e] = bv;
        PSTREAM_1(rw3, 1536, j0, (H2 + e * 64), 0, 64, EPB)
        #pragma unroll
        for (int e = 0; e < EPB; e++) *(float4*)&rad0[e * 640 + j0] = acc[e];
    }
    __syncthreads();
    {
        float* X  = R;
        float* WG = R + 3200;
        for (int e = 0; e < EPB; e++) {
            int s_ = senders[e0 + e], r_ = receivers[e0 + e];
            for (int q = t; q < 800; q += 256) {
                int k = q >> 5, c0 = (q & 31) * 4;
                float4 v = (c0 < 64) ? LD4<BF>(node_feats, (size_t)s_ * 1600 + k * 64 + c0)
                                     : LD4<BF>(node_feats, (size_t)r_ * 1600 + k * 64 + (c0 - 64));
                *(float4*)&X[q * 4] = v;
            }
            for (int i = t; i < 125; i += 256) WG[i] = LD1<BF>(wigner, (size_t)(e0 + e) * 475 + i);
            __syncthreads();
            if (t < 160) {
                int m = t >> 5, c0 = (t & 31) * 4;
                float4 acc = make_float4(0.f, 0.f, 0.f, 0.f);
                #pragma unroll
                for (int k = 0; k < 25; k++) fma4(acc, WG[m * 25 + k], *(const float4*)&X[k * 128 + c0]);
                float4 rv = *(const float4*)&rad0[e * 640 + t * 4];
                acc.x *= rv.x; acc.y *= rv.y; acc.z *= rv.z; acc.w *= rv.w;
                *(float4*)&x0[e * 640 + t * 4] = acc;
            }
            __syncthreads();
        }
    }
    {
        float* Y = R;
        int col = t & 63, kq = t >> 6;
        int j0 = 320 + col * 4;
        int ibase = kq * 160;
        float4 acc[EPB];
        #pragma unroll
        for (int e = 0; e < EPB; e++) acc[e] = make_float4(0.f, 0.f, 0.f, 0.f);
        PSTREAM_1(c1w0, 640, j0, (x0 + e * 640), ibase, 160, EPB)
        __syncthreads();
        #pragma unroll
        for (int e = 0; e < EPB; e++) *(float4*)&Y[(e * 256 + kq * 64 + col) * 4] = acc[e];
        __syncthreads();
        {
            int e = t >> 6, c = t & 63;
            float4 s = LD4<BF>(c1b0, 320 + c * 4);
            #pragma unroll
            for (int q = 0; q < 4; q++) {
                float4 v = *(const float4*)&Y[(e * 256 + q * 64 + c) * 4];
                s.x += v.x; s.y += v.y; s.z += v.z; s.w += v.w;
            }
            *(float4*)&extraA[e * 256 + c * 4] = s;
        }
    }
    __syncthreads();
    if (t < 32) {
        int e = t >> 3, h = t & 7;
        float mu = 0.0f;
        for (int k = 0; k < 32; k++) mu += extraA[e * 256 + h * 32 + k];
        mu *= (1.0f / 32.0f);
        float var = 0.0f;
        for (int k = 0; k < 32; k++) { float d = extraA[e * 256 + h * 32 + k] - mu; var += d * d; }
        float rs = rsqrtf(var * (1.0f / 32.0f) + 1e-6f);
        float logit = 0.0f;
        for (int k = 0; k < 32; k++) {
            float xn = (extraA[e * 256 + h * 32 + k] - mu) * rs * LD1<BF>(an_s, k) + LD1<BF>(an_b, k);
            float slr = 0.6f * xn + 0.4f * xn * (2.0f * sigmf(xn) - 1.0f);
            logit += slr * LD1<BF>(adot, h * 32 + k);
        }
        int r = receivers[e0 + e];
        alpha_out[(size_t)(e0 + e) * 8 + h] = logit;
        atomicMax(&nmax[r * 8 + h], encF(logit));
    }
}

// ---------------- exp + denom ----------------
__global__ void k_exp(const int* __restrict__ receivers, const unsigned* __restrict__ nmax,
                      float* __restrict__ alpha, float* __restrict__ nden) {
    int tid = blockIdx.x * 256 + threadIdx.x;
    if (tid >= EDGES * 8) return;
    int e = tid >> 3, h = tid & 7;
    int r = receivers[e];
    float m = decF(nmax[r * 8 + h]);
    float ex = expf(alpha[tid] - m);
    alpha[tid] = ex;
    atomicAdd(&nden[r * 8 + h], ex);
}

// ---------------- mega2: 4 edges per block, 512 threads ----------------
// LDS map: identical to r6 (verified). 78976 B -> 2 blocks/CU = 16 waves/CU.
template<bool BF>
__global__ __launch_bounds__(512, 4) void k_mega2(
    const void* __restrict__ node_feats, const void* __restrict__ edge_dist,
    const void* __restrict__ wigner, const void* __restrict__ wigner_inv,
    const void* __restrict__ to_grid, const void* __restrict__ from_grid,
    const void* __restrict__ emb_s, const void* __restrict__ emb_r,
    const void* __restrict__ rw1, const void* __restrict__ rb1,
    const void* __restrict__ rl1s, const void* __restrict__ rl1b,
    const void* __restrict__ rw2, const void* __restrict__ rb2,
    const void* __restrict__ rl2s, const void* __restrict__ rl2b,
    const void* __restrict__ rw3, const void* __restrict__ rb3,
    const void* __restrict__ c1w0, const void* __restrict__ c1b0,
    const void* __restrict__ c1w1, const void* __restrict__ c1w2,
    const void* __restrict__ c2w0, const void* __restrict__ c2b0,
    const void* __restrict__ c2w1, const void* __restrict__ c2w2,
    const void* __restrict__ proj_w,
    const int* __restrict__ species, const int* __restrict__ senders,
    const int* __restrict__ receivers, const int* __restrict__ dtf,
    const float* __restrict__ alpha, const float* __restrict__ nden,
    float* __restrict__ accb)
{
    if ((*dtf != 0) != BF) return;
    __shared__ __align__(16) float sm[19744];
    float* Q   = sm;
    float* C   = sm + 9728;
    float* RAD = sm + 13408;
    float* YF  = sm + 14592;
    float* GAT = sm + 19456;
    float* ALs = sm + 19712;

    const int t = threadIdx.x;
    const int e0 = blockIdx.x * EPB;
    int rcv[EPB];
    #pragma unroll
    for (int e = 0; e < EPB; e++) rcv[e] = receivers[e0 + e];

    // ---- P1: radial MLP ----
    {
        float* XE = C;
        float* T1 = C + 768;
        float* H1 = C + 1024;
        float* T2 = C + 1280;
        float* H2 = C + 1536;
        for (int i = t; i < 768; i += 512) {
            int e = i / 192, j = i - e * 192;
            int ee = e0 + e;
            float v;
            if (j < 64)       v = LD1<BF>(edge_dist, (size_t)ee * 64 + j);
            else if (j < 128) v = LD1<BF>(emb_s, (size_t)species[senders[ee]] * 64 + (j - 64));
            else              v = LD1<BF>(emb_r, (size_t)species[receivers[ee]] * 64 + (j - 128));
            XE[e * 192 + j] = v;
        }
        __syncthreads();
        const int eg = t >> 6, tt = t & 63;
        if (t < 256) {
            float a = LD1<BF>(rb1, tt);
            #pragma unroll 4
            for (int k = 0; k < 192; k++) a += XE[eg * 192 + k] * LD1<BF>(rw1, k * 64 + tt);
            T1[eg * 64 + tt] = a;
        }
        __syncthreads();
        if (t < 256) {
            float mu = 0.f;
            for (int k = 0; k < 64; k++) mu += T1[eg * 64 + k];
            mu *= (1.f / 64.f);
            float var = 0.f;
            for (int k = 0; k < 64; k++) { float d = T1[eg * 64 + k] - mu; var += d * d; }
            float xn = (T1[eg * 64 + tt] - mu) * rsqrtf(var * (1.f / 64.f) + 1e-6f) * LD1<BF>(rl1s, tt) + LD1<BF>(rl1b, tt);
            H1[eg * 64 + tt] = xn * sigmf(xn);
        }
        __syncthreads();
        if (t < 256) {
            float a = LD1<BF>(rb2, tt);
            #pragma unroll 4
            for (int k = 0; k < 64; k++) a += H1[eg * 64 + k] * LD1<BF>(rw2, k * 64 + tt);
            T2[eg * 64 + tt] = a;
        }
        __syncthreads();
        if (t < 256) {
            float mu = 0.f;
            for (int k = 0; k < 64; k++) mu += T2[eg * 64 + k];
            mu *= (1.f / 64.f);
            float var = 0.f;
            for (int k = 0; k < 64; k++) { float d = T2[eg * 64 + k] - mu; var += d * d; }
            float xn = (T2[eg * 64 + tt] - mu) * rsqrtf(var * (1.f / 64.f) + 1e-6f) * LD1<BF>(rl2s, tt) + LD1<BF>(rl2b, tt);
            H2[eg * 64 + tt] = xn * sigmf(xn);
        }
        __syncthreads();
        if (t < 384) {
            int j0 = t * 4;
            float4 acc[EPB];
            float4 bv = LD4<BF>(rb3, j0);
            #pragma unroll
            for (int e = 0; e < EPB; e++) acc[e] = bv;
            PSTREAM_1(rw3, 1536, j0, (H2 + e * 64), 0, 64, EPB)
            #pragma unroll
            for (int e = 0; e < EPB; e++) *(float4*)&RAD[e * 1536 + j0] = acc[e];
        }
        __syncthreads();
    }

    // ---- P2: gather + wigner rotate + rad scale (per edge sequential) ----
    {
        float* X  = C;          // 3200
        float* WG = C + 3200;   // 480
        for (int e = 0; e < EPB; e++) {
            int s_ = senders[e0 + e], r_ = receivers[e0 + e];
            for (int q = t; q < 800; q += 512) {
                int k = q >> 5, c0 = (q & 31) * 4;
                float4 v = (c0 < 64) ? LD4<BF>(node_feats, (size_t)s_ * 1600 + k * 64 + c0)
                                     : LD4<BF>(node_feats, (size_t)r_ * 1600 + k * 64 + (c0 - 64));
                *(float4*)&X[q * 4] = v;
            }
            if (t < 475) WG[t] = LD1<BF>(wigner, (size_t)(e0 + e) * 475 + t);
            __syncthreads();
            for (int q = t; q < 608; q += 512) {
                int m = q >> 5, c0 = (q & 31) * 4;
                float4 acc = make_float4(0.f, 0.f, 0.f, 0.f);
                #pragma unroll
                for (int k = 0; k < 25; k++) fma4(acc, WG[m * 25 + k], *(const float4*)&X[k * 128 + c0]);
                int ri0;
                if (m < 5)       ri0 = m * 128 + c0;
                else if (m < 13) ri0 = 640 + ((m - 5) & 3) * 128 + c0;
                else             ri0 = 1152 + ((m - 13) % 3) * 128 + c0;
                float4 rv = *(const float4*)&RAD[e * 1536 + ri0];
                acc.x *= rv.x; acc.y *= rv.y; acc.z *= rv.z; acc.w *= rv.w;
                *(float4*)&Q[e * 2432 + q * 4] = acc;
            }
            __syncthreads();
        }
    }

    float4 ra[EPB], rb[EPB];

    // ---- P3: conv1 (512-thread schedule) ----
    {
        float* EF2 = C;
        float* YM  = YF;  // m1 staging [e][r][512] = 4096 floats
        // stage A: m1 with (row, colgroup, k-half) = 2x128x2 = 512 threads
        {
            int cg = t & 127, r = (t >> 7) & 1, kh = t >> 8;
            int j0 = cg * 4;
            float4 acc[EPB];
            #pragma unroll
            for (int e = 0; e < EPB; e++) acc[e] = make_float4(0.f, 0.f, 0.f, 0.f);
            int kb0 = 256 * kh;
            PSTREAM_1(c1w1, 512, j0, (Q + e * 2432 + 640 + 512 * r), kb0, 256, EPB)
            if (kh == 1) {
                #pragma unroll
                for (int e = 0; e < EPB; e++) *(float4*)&YM[(e * 2 + r) * 512 + j0] = acc[e];
            }
            __syncthreads();
            if (kh == 0) {
                #pragma unroll
                for (int e = 0; e < EPB; e++) {
                    float4 p = *(const float4*)&YM[(e * 2 + r) * 512 + j0];
                    acc[e].x += p.x; acc[e].y += p.y; acc[e].z += p.z; acc[e].w += p.w;
                    *(float4*)&YM[(e * 2 + r) * 512 + j0] = acc[e];
                }
            }
            __syncthreads();
            for (int u = t; u < 1024; u += 512) {
                int e = u >> 8, j = u & 255;
                float y0l = YM[(e * 2 + 0) * 512 + j];
                float y0u = YM[(e * 2 + 0) * 512 + 256 + j];
                float y1l = YM[(e * 2 + 1) * 512 + j];
                float y1u = YM[(e * 2 + 1) * 512 + 256 + j];
                EF2[e * 1216 + 320 + j] = y0l - y1u;
                EF2[e * 1216 + 576 + j] = y1l + y0u;
            }
            __syncthreads();
        }
        // stage B: m0 k-split (2 kh x 96 jq = 192 thr) || m2 single-row (192 thr)
        // NOTE: m0 has exactly 96 output f4-groups: 80 -> EF2[0,320), 16 -> GAT
        {
            float* MS  = YF;          // m0 kh=1 partials [e][96] f4 = 1536
            float* M2S = YF + 1536;   // m2 upper stage [e][r][48] f4 = 1536
            float4 keep[EPB];
            #pragma unroll
            for (int e = 0; e < EPB; e++) keep[e] = make_float4(0.f, 0.f, 0.f, 0.f);
            if (t < 192) {
                int kh = (t >= 96) ? 1 : 0;
                int jq = t - 96 * kh;  // 0..95
                int cmj = (jq < 80) ? jq * 4 : 576 + (jq - 80) * 4;
                float4 acc[EPB];
                #pragma unroll
                for (int e = 0; e < EPB; e++) acc[e] = make_float4(0.f, 0.f, 0.f, 0.f);
                int kb0 = kh * 320;
                PSTREAM_1(c1w0, 640, cmj, (Q + e * 2432), kb0, 320, EPB)
                if (kh) {
                    #pragma unroll
                    for (int e = 0; e < EPB; e++) *(float4*)&MS[(e * 96 + jq) * 4] = acc[e];
                } else {
                    #pragma unroll
                    for (int e = 0; e < EPB; e++) keep[e] = acc[e];
                }
            } else if (t < 384) {
                int u = t - 192;
                int r = (u >= 96) ? 1 : 0, cg = u - 96 * r;  // 0..95
                int j0 = cg * 4;
                float4 acc[EPB];
                #pragma unroll
                for (int e = 0; e < EPB; e++) acc[e] = make_float4(0.f, 0.f, 0.f, 0.f);
                int abase = 1664 + 384 * r;
                PSTREAM_1(c1w2, 384, j0, (Q + e * 2432 + abase), 0, 384, EPB)
                if (cg >= 48) {
                    #pragma unroll
                    for (int e = 0; e < EPB; e++)
                        *(float4*)&M2S[((e * 2 + r) * 48 + (cg - 48)) * 4] = acc[e];
                } else {
                    #pragma unroll
                    for (int e = 0; e < EPB; e++) keep[e] = acc[e];
                }
            }
            __syncthreads();
            if (t < 96) {  // m0 combine (kh=0 threads)
                int jq = t;
                int cmj = (jq < 80) ? jq * 4 : 576 + (jq - 80) * 4;
                float4 bv = LD4<BF>(c1b0, cmj);
                #pragma unroll
                for (int e = 0; e < EPB; e++) {
                    float4 p = *(const float4*)&MS[(e * 96 + jq) * 4];
                    float4 v;
                    v.x = keep[e].x + p.x + bv.x; v.y = keep[e].y + p.y + bv.y;
                    v.z = keep[e].z + p.z + bv.z; v.w = keep[e].w + p.w + bv.w;
                    if (jq < 80) *(float4*)&EF2[e * 1216 + jq * 4] = v;
                    else         *(float4*)&GAT[e * 64 + (jq - 80) * 4] = v;
                }
            } else if (t >= 192 && t < 384) {  // m2 combine (cg < 48)
                int u = t - 192;
                int r = (u >= 96) ? 1 : 0, cg = u - 96 * r;
                if (cg < 48) {
                    int j0 = cg * 4;
                    #pragma unroll
                    for (int e = 0; e < EPB; e++) {
                        float4 o = *(const float4*)&M2S[((e * 2 + (1 - r)) * 48 + cg) * 4];
                        float4 v;
                        if (r == 0) {
                            v.x = keep[e].x - o.x; v.y = keep[e].y - o.y;
                            v.z = keep[e].z - o.z; v.w = keep[e].w - o.w;
                            *(float4*)&EF2[e * 1216 + 832 + j0] = v;
                        } else {
                            v.x = keep[e].x + o.x; v.y = keep[e].y + o.y;
                            v.z = keep[e].z + o.z; v.w = keep[e].w + o.w;
                            *(float4*)&EF2[e * 1216 + 1024 + j0] = v;
                        }
                    }
                }
            }
            __syncthreads();
        }
    }

    // ---- P4: grid nonlinearity (per edge, 512-wide) ----
    {
        float* FE  = YF;        // FEATS [e][1216]
        float* G   = Q;         // 100 x 64 = 6400
        float* S2  = Q + 6400;  // 608 f4 = 2432
        float* EF2 = C;
        for (int e = 0; e < EPB; e++) {
            for (int idx = t; idx < 1600; idx += 512) {
                int gi = idx >> 4, c0 = (idx & 15) * 4;
                float4 acc = make_float4(0.f, 0.f, 0.f, 0.f);
                #pragma unroll
                for (int m = 0; m < 19; m++)
                    fma4(acc, LD1<BF>(to_grid, gi * 19 + m),
                         *(const float4*)&EF2[e * 1216 + m * 64 + c0]);
                silu4(acc);
                *(float4*)&G[gi * 64 + c0] = acc;
            }
            __syncthreads();
            for (int idx = t; idx < 608; idx += 512) {
                int m = idx >> 5, cq = (idx >> 1) & 15, h = idx & 1, c0 = cq * 4;
                int g0 = h * 50;
                float4 acc = make_float4(0.f, 0.f, 0.f, 0.f);
                #pragma unroll 5
                for (int gi = 0; gi < 50; gi++)
                    fma4(acc, LD1<BF>(from_grid, (g0 + gi) * 19 + m),
                         *(const float4*)&G[(g0 + gi) * 64 + c0]);
                *(float4*)&S2[idx * 4] = acc;
            }
            __syncthreads();
            if (t < 304) {
                int m = t >> 4, cq = t & 15;
                int pb = (m * 32 + cq * 2) * 4;
                float4 a = *(const float4*)&S2[pb];
                float4 b = *(const float4*)&S2[pb + 4];
                a.x += b.x; a.y += b.y; a.z += b.z; a.w += b.w;
                *(float4*)&FE[e * 1216 + m * 64 + cq * 4] = a;
            }
            __syncthreads();
        }
        if (t < 64) {
            #pragma unroll
            for (int e = 0; e < EPB; e++) { float x = GAT[e * 64 + t]; FE[e * 1216 + t] = x * sigmf(x); }
        }
        __syncthreads();
    }

    // ---- P5: conv2 -> EF3 in Q (512-thread schedule) ----
    {
        float* FE  = YF;
        float* M1S = C;   // m1 upper stage [e][r][128] f4 = 4096
        float4 keep[EPB];
        {
            int cg = t & 255, r = t >> 8;
            int j0 = cg * 4;
            float4 acc[EPB];
            #pragma unroll
            for (int e = 0; e < EPB; e++) acc[e] = make_float4(0.f, 0.f, 0.f, 0.f);
            int abase = 320 + 256 * r;
            PSTREAM_1(c2w1, 1024, j0, (FE + e * 1216 + abase), 0, 256, EPB)
            if (cg >= 128) {
                #pragma unroll
                for (int e = 0; e < EPB; e++)
                    *(float4*)&M1S[((e * 2 + r) * 128 + (cg - 128)) * 4] = acc[e];
            } else {
                #pragma unroll
                for (int e = 0; e < EPB; e++) keep[e] = acc[e];
            }
            __syncthreads();
            if (cg < 128) {
                #pragma unroll
                for (int e = 0; e < EPB; e++) {
                    float4 o = *(const float4*)&M1S[((e * 2 + (1 - r)) * 128 + cg) * 4];
                    float4 v;
                    if (r == 0) {
                        v.x = keep[e].x - o.x; v.y = keep[e].y - o.y;
                        v.z = keep[e].z - o.z; v.w = keep[e].w - o.w;
                        *(float4*)&Q[e * 2432 + 640 + j0] = v;
                    } else {
                        v.x = keep[e].x + o.x; v.y = keep[e].y + o.y;
                        v.z = keep[e].z + o.z; v.w = keep[e].w + o.w;
                        *(float4*)&Q[e * 2432 + 1152 + j0] = v;
                    }
                }
            }
            __syncthreads();
        }
        // stage B: m0 (t<160 full-k) || m2 both-rows (160<=t<352)
        {
            float* M2S = C;  // m2 upper stage [e][r][96] f4 = 3072
            if (t < 160) {
                int j0 = t * 4;
                float4 acc[EPB];
                float4 bv = LD4<BF>(c2b0, j0);
                #pragma unroll
                for (int e = 0; e < EPB; e++) acc[e] = bv;
                PSTREAM_1(c2w0, 640, j0, (FE + e * 1216), 0, 320, EPB)
                #pragma unroll
                for (int e = 0; e < EPB; e++) *(float4*)&Q[e * 2432 + j0] = acc[e];
            } else if (t < 352) {
                int cg = t - 160;  // 0..191
                int j0 = cg * 4;
                #pragma unroll
                for (int e = 0; e < EPB; e++) { ra[e] = make_float4(0,0,0,0); rb[e] = make_float4(0,0,0,0); }
                PSTREAM_2(c2w2, 768, j0, (FE + e * 1216 + 832), (FE + e * 1216 + 1024), 192)
                if (cg >= 96) {
                    #pragma unroll
                    for (int e = 0; e < EPB; e++) {
                        *(float4*)&M2S[((e * 2 + 0) * 96 + (cg - 96)) * 4] = ra[e];
                        *(float4*)&M2S[((e * 2 + 1) * 96 + (cg - 96)) * 4] = rb[e];
                    }
                }
            }
            __syncthreads();
            if (t >= 160 && t < 256) {
                int cg = t - 160;  // 0..95
                int j0 = cg * 4;
                #pragma unroll
                for (int e = 0; e < EPB; e++) {
                    float4 y1u = *(const float4*)&M2S[((e * 2 + 1) * 96 + cg) * 4];
                    float4 y0u = *(const float4*)&M2S[((e * 2 + 0) * 96 + cg) * 4];
                    float4 r, im;
                    r.x = ra[e].x - y1u.x; r.y = ra[e].y - y1u.y;
                    r.z = ra[e].z - y1u.z; r.w = ra[e].w - y1u.w;
                    im.x = rb[e].x + y0u.x; im.y = rb[e].y + y0u.y;
                    im.z = rb[e].z + y0u.z; im.w = rb[e].w + y0u.w;
                    *(float4*)&Q[e * 2432 + 1664 + j0] = r;
                    *(float4*)&Q[e * 2432 + 2048 + j0] = im;
                }
            }
            __syncthreads();
        }
    }

    // ---- P7: wigner_inv rotate + alpha + fused proj (edge-split proj) ----
    {
        float* WV = C;           // [e][480]
        float* EO = C + 1920;    // up to 13*512 = 6656 floats
        if (t < 32) {
            int h = t & 7;
            int ee = e0 + (t >> 3);
            ALs[t] = alpha[(size_t)ee * 8 + h] / (nden[(size_t)receivers[ee] * 8 + h] + 1e-16f);
        }
        for (int i = t; i < 1900; i += 512) {
            int e = i / 475, j = i - e * 475;
            WV[e * 480 + j] = LD1<BF>(wigner_inv, (size_t)(e0 + e) * 475 + j);
        }
        __syncthreads();
        for (int kb = 0; kb < 25; kb += 13) {
            const int nk = (kb == 0) ? 13 : 12;
            for (int u = t; u < nk * 128; u += 512) {
                int e = u & 3, idx = u >> 2;
                int ki = idx >> 5, c0 = (idx & 31) * 4;
                int k = kb + ki;
                float4 acc = make_float4(0.f, 0.f, 0.f, 0.f);
                #pragma unroll
                for (int m = 0; m < 19; m++)
                    fma4(acc, WV[e * 480 + k * 19 + m], *(const float4*)&Q[e * 2432 + m * 128 + c0]);
                float al = ALs[e * 8 + (c0 >> 4)];
                int b = (ki * 128 + c0) * 4 + e;
                EO[b + 0]  = acc.x * al;
                EO[b + 4]  = acc.y * al;
                EO[b + 8]  = acc.z * al;
                EO[b + 12] = acc.w * al;
            }
            __syncthreads();
            if (t < nk * 32) {
                int ki = t >> 5;
                int rem = t & 31;
                int o = rem >> 1, eh = rem & 1;
                int o0 = o * 4;
                int k = kb + ki;
                int l = (k == 0) ? 0 : (k < 4) ? 1 : (k < 9) ? 2 : (k < 16) ? 3 : 4;
                float4 pa0 = make_float4(0,0,0,0), pa1 = pa0;
                const float* eob = &EO[ki * 512 + eh * 2];
                size_t base = (size_t)l * 8192 + o0;
                // prefetched proj_w stream (double-buffered)
                float4 qA0, qA1, qA2, qA3, qB0, qB1, qB2, qB3;
                qA0 = LD4<BF>(proj_w, base + (size_t)0 * 64);
                qA1 = LD4<BF>(proj_w, base + (size_t)1 * 64);
                qA2 = LD4<BF>(proj_w, base + (size_t)2 * 64);
                qA3 = LD4<BF>(proj_w, base + (size_t)3 * 64);
                int c = 0;
                #define PROJ_FMA(PD, cc) \
                    fma4(pa0, eob[((cc) + 0) * 4], PD##0); fma4(pa1, eob[((cc) + 0) * 4 + 1], PD##0); \
                    fma4(pa0, eob[((cc) + 1) * 4], PD##1); fma4(pa1, eob[((cc) + 1) * 4 + 1], PD##1); \
                    fma4(pa0, eob[((cc) + 2) * 4], PD##2); fma4(pa1, eob[((cc) + 2) * 4 + 1], PD##2); \
                    fma4(pa0, eob[((cc) + 3) * 4], PD##3); fma4(pa1, eob[((cc) + 3) * 4 + 1], PD##3);
                for (; c + 8 < 128; c += 8) {
                    qB0 = LD4<BF>(proj_w, base + (size_t)(c + 4) * 64);
                    qB1 = LD4<BF>(proj_w, base + (size_t)(c + 5) * 64);
                    qB2 = LD4<BF>(proj_w, base + (size_t)(c + 6) * 64);
                    qB3 = LD4<BF>(proj_w, base + (size_t)(c + 7) * 64);
                    PROJ_FMA(qA, c)
                    qA0 = LD4<BF>(proj_w, base + (size_t)(c + 8) * 64);
                    qA1 = LD4<BF>(proj_w, base + (size_t)(c + 9) * 64);
                    qA2 = LD4<BF>(proj_w, base + (size_t)(c + 10) * 64);
                    qA3 = LD4<BF>(proj_w, base + (size_t)(c + 11) * 64);
                    PROJ_FMA(qB, (c + 4))
                }
                qB0 = LD4<BF>(proj_w, base + (size_t)(c + 4) * 64);
                qB1 = LD4<BF>(proj_w, base + (size_t)(c + 5) * 64);
                qB2 = LD4<BF>(proj_w, base + (size_t)(c + 6) * 64);
                qB3 = LD4<BF>(proj_w, base + (size_t)(c + 7) * 64);
                PROJ_FMA(qA, c)
                PROJ_FMA(qB, (c + 4))
                #undef PROJ_FMA
                int ep = eh * 2;
                float* d0 = &accb[(size_t)rcv[ep] * 1600 + k * 64 + o0];
                atomicAdd(d0 + 0, pa0.x); atomicAdd(d0 + 1, pa0.y);
                atomicAdd(d0 + 2, pa0.z); atomicAdd(d0 + 3, pa0.w);
                float* d1 = &accb[(size_t)rcv[ep + 1] * 1600 + k * 64 + o0];
                atomicAdd(d1 + 0, pa1.x); atomicAdd(d1 + 1, pa1.y);
                atomicAdd(d1 + 2, pa1.z); atomicAdd(d1 + 3, pa1.w);
            }
            __syncthreads();
        }
    }
}

// ---------------- bias + convert ----------------
template<bool BF>
__global__ void k_out(const float* __restrict__ accb, const void* __restrict__ proj_b,
                      void* __restrict__ out, const int* __restrict__ dtf) {
    if ((*dtf != 0) != BF) return;
    int i = blockIdx.x * 256 + threadIdx.x;
    if (i >= NNODES * 1600) return;
    int r = i % 1600;
    int m = r >> 6, o = r & 63;
    float v = accb[i] + ((m == 0) ? LD1<BF>(proj_b, o) : 0.0f);
    if (BF) ((bf16*)out)[i] = __float2bfloat16(v);
    else    ((float*)out)[i] = v;
}

extern "C" void kernel_launch(void* const* d_in, const int* in_sizes, int n_in,
                              void* d_out, int out_size, void* d_ws, size_t ws_size,
                              hipStream_t stream) {
    const void* node_feats = d_in[0];
    const void* edge_dist  = d_in[1];
    const void* wigner     = d_in[2];
    const void* wigner_inv = d_in[3];
    const void* to_grid    = d_in[4];
    const void* from_grid  = d_in[5];
    const void* emb_s      = d_in[6];
    const void* emb_r      = d_in[7];
    const void* rw1  = d_in[8];
    const void* rb1  = d_in[9];
    const void* rl1s = d_in[10];
    const void* rl1b = d_in[11];
    const void* rw2  = d_in[12];
    const void* rb2  = d_in[13];
    const void* rl2s = d_in[14];
    const void* rl2b = d_in[15];
    const void* rw3  = d_in[16];
    const void* rb3  = d_in[17];
    const void* c1w0 = d_in[18];
    const void* c1b0 = d_in[19];
    const void* c1w1 = d_in[20];
    const void* c1w2 = d_in[21];
    const void* c2w0 = d_in[22];
    const void* c2b0 = d_in[23];
    const void* c2w1 = d_in[24];
    const void* c2w2 = d_in[25];
    const void* an_s = d_in[26];
    const void* an_b = d_in[27];
    const void* adot = d_in[28];
    const void* proj_w = d_in[29];
    const void* proj_b = d_in[30];
    const int* species   = (const int*)d_in[31];
    const int* senders   = (const int*)d_in[32];
    const int* receivers = (const int*)d_in[33];

    char* ws = (char*)d_ws;
    float*    accb  = (float*)ws;                   // 32,000,000 B
    float*    alpha = (float*)(ws + 32000000);      // 800,000 B
    unsigned* nmax  = (unsigned*)(ws + 32800000);   // 160,000 B
    float*    nden  = (float*)(ws + 32960000);      // 160,000 B
    int*      dtf   = (int*)(ws + 33120000);        // 4 B

    k_detect<<<1, 64, 0, stream>>>(edge_dist, dtf);
    k_fill<<<(NNODES * 1600 + 255) / 256, 256, 0, stream>>>(accb, nden, nmax);

    k_alpha<true><<<NBLK, 256, 0, stream>>>(
        node_feats, edge_dist, wigner, emb_s, emb_r,
        rw1, rb1, rl1s, rl1b, rw2, rb2, rl2s, rl2b, rw3, rb3,
        c1w0, c1b0, an_s, an_b, adot, species, senders, receivers, dtf,
        alpha, nmax);
    k_alpha<false><<<NBLK, 256, 0, stream>>>(
        node_feats, edge_dist, wigner, emb_s, emb_r,
        rw1, rb1, rl1s, rl1b, rw2, rb2, rl2s, rl2b, rw3, rb3,
        c1w0, c1b0, an_s, an_b, adot, species, senders, receivers, dtf,
        alpha, nmax);

    k_exp<<<(EDGES * 8 + 255) / 256, 256, 0, stream>>>(receivers, nmax, alpha, nden);

    k_mega2<true><<<NBLK, 512, 0, stream>>>(
        node_feats, edge_dist, wigner, wigner_inv, to_grid, from_grid, emb_s, emb_r,
        rw1, rb1, rl1s, rl1b, rw2, rb2, rl2s, rl2b, rw3, rb3,
        c1w0, c1b0, c1w1, c1w2, c2w0, c2b0, c2w1, c2w2, proj_w,
        species, senders, receivers, dtf, alpha, nden, accb);
    k_mega2<false><<<NBLK, 512, 0, stream>>>(
        node_feats, edge_dist, wigner, wigner_inv, to_grid, from_grid, emb_s, emb_r,
        rw1, rb1, rl1s, rl1b, rw2, rb2, rl2s, rl2b, rw3, rb3,
        c1w0, c1b0, c1w1, c1w2, c2w0, c2b0, c2w1, c2w2, proj_w,
        species, senders, receivers, dtf, alpha, nden, accb);

    k_out<true><<<(NNODES * 1600 + 255) / 256, 256, 0, stream>>>(accb, proj_b, d_out, dtf);
    k_out<false><<<(NNODES * 1600 + 255) / 256, 256, 0, stream>>>(accb, proj_b, d_out, dtf);
}

// Round 8
// 4405.838 us; speedup vs baseline: 1.0016x; 1.0016x over previous
//
#include <hip/hip_runtime.h>
#include <hip/hip_bf16.h>

using bf16 = __hip_bfloat16;

#define EDGES 25000
#define NNODES 5000
#define EPB 4
#define NBLK (EDGES / EPB)

__device__ __forceinline__ float sigmf(float x) { return 1.0f / (1.0f + expf(-x)); }

template<bool BF>
__device__ __forceinline__ float LD1(const void* p, size_t i) {
    if (BF) return __bfloat162float(((const bf16*)p)[i]);
    else    return ((const float*)p)[i];
}

template<bool BF>
__device__ __forceinline__ float4 LD4(const void* p, size_t i) {
    if (BF) {
        ushort4 u = *reinterpret_cast<const ushort4*>((const bf16*)p + i);
        float4 r;
        r.x = __uint_as_float((unsigned)u.x << 16);
        r.y = __uint_as_float((unsigned)u.y << 16);
        r.z = __uint_as_float((unsigned)u.z << 16);
        r.w = __uint_as_float((unsigned)u.w << 16);
        return r;
    } else {
        return *reinterpret_cast<const float4*>((const float*)p + i);
    }
}

__device__ __forceinline__ void fma4(float4& a, float s, const float4& w) {
    a.x += s * w.x; a.y += s * w.y; a.z += s * w.z; a.w += s * w.w;
}

__device__ __forceinline__ void silu4(float4& a) {
    a.x *= sigmf(a.x); a.y *= sigmf(a.y); a.z *= sigmf(a.z); a.w *= sigmf(a.w);
}

// monotone float<->uint encoding for atomicMax on floats
__device__ __forceinline__ unsigned encF(float f) {
    unsigned b = __float_as_uint(f);
    return (b & 0x80000000u) ? ~b : (b | 0x80000000u);
}
__device__ __forceinline__ float decF(unsigned e) {
    unsigned b = (e & 0x80000000u) ? (e ^ 0x80000000u) : ~e;
    return __uint_as_float(b);
}
#define ENC_NEGINF 0x007FFFFFu

// ---- cross-batch double-buffered weight streaming (2-stage SW pipeline) ----
#define PLOAD4(WD, Wptr, LDW, j0, ii) \
    WD##0 = LD4<BF>(Wptr, (size_t)(ii + 0) * (LDW) + (j0)); \
    WD##1 = LD4<BF>(Wptr, (size_t)(ii + 1) * (LDW) + (j0)); \
    WD##2 = LD4<BF>(Wptr, (size_t)(ii + 2) * (LDW) + (j0)); \
    WD##3 = LD4<BF>(Wptr, (size_t)(ii + 3) * (LDW) + (j0));

#define PFMA_1(WD, ABASE, ii, NACC) \
    _Pragma("unroll") \
    for (int e = 0; e < NACC; e++) { \
        float4 a0 = *(const float4*)((ABASE) + (ii)); \
        fma4(acc[e], a0.x, WD##0); fma4(acc[e], a0.y, WD##1); \
        fma4(acc[e], a0.z, WD##2); fma4(acc[e], a0.w, WD##3); \
    }

// KLEN must be a multiple of 8. acc[NACC] must be live.
#define PSTREAM_1(Wptr, LDW, j0, ABASE, KBASE, KLEN, NACC) \
    { \
        float4 wA0, wA1, wA2, wA3, wB0, wB1, wB2, wB3; \
        int i = (KBASE); \
        const int iend = (KBASE) + (KLEN); \
        PLOAD4(wA, Wptr, LDW, j0, i) \
        for (; i + 8 < iend; i += 8) { \
            PLOAD4(wB, Wptr, LDW, j0, (i + 4)) \
            PFMA_1(wA, ABASE, i, NACC) \
            PLOAD4(wA, Wptr, LDW, j0, (i + 8)) \
            PFMA_1(wB, ABASE, (i + 4), NACC) \
        } \
        PLOAD4(wB, Wptr, LDW, j0, (i + 4)) \
        PFMA_1(wA, ABASE, i, NACC) \
        PFMA_1(wB, ABASE, (i + 4), NACC) \
    }

#define PFMA_2(WD, ABASEA, ABASEB, ii) \
    _Pragma("unroll") \
    for (int e = 0; e < EPB; e++) { \
        float4 a0 = *(const float4*)((ABASEA) + (ii)); \
        float4 b0 = *(const float4*)((ABASEB) + (ii)); \
        fma4(ra[e], a0.x, WD##0); fma4(ra[e], a0.y, WD##1); \
        fma4(ra[e], a0.z, WD##2); fma4(ra[e], a0.w, WD##3); \
        fma4(rb[e], b0.x, WD##0); fma4(rb[e], b0.y, WD##1); \
        fma4(rb[e], b0.z, WD##2); fma4(rb[e], b0.w, WD##3); \
    }

// two-row variant into ra[e], rb[e]; KLEN multiple of 8, KBASE = 0
#define PSTREAM_2(Wptr, LDW, j0, ABASEA, ABASEB, KLEN) \
    { \
        float4 wA0, wA1, wA2, wA3, wB0, wB1, wB2, wB3; \
        int i = 0; \
        const int iend = (KLEN); \
        PLOAD4(wA, Wptr, LDW, j0, i) \
        for (; i + 8 < iend; i += 8) { \
            PLOAD4(wB, Wptr, LDW, j0, (i + 4)) \
            PFMA_2(wA, ABASEA, ABASEB, i) \
            PLOAD4(wA, Wptr, LDW, j0, (i + 8)) \
            PFMA_2(wB, ABASEA, ABASEB, (i + 4)) \
        } \
        PLOAD4(wB, Wptr, LDW, j0, (i + 4)) \
        PFMA_2(wA, ABASEA, ABASEB, i) \
        PFMA_2(wB, ABASEA, ABASEB, (i + 4)) \
    }

// ---------------- dtype detector ----------------
__global__ void k_detect(const void* edge_dist, int* flag) {
    if (threadIdx.x == 0 && blockIdx.x == 0) {
        const bf16* p = (const bf16*)edge_dist;
        int ok = 1;
        for (int i = 0; i < 256; i++) {
            float v = __bfloat162float(p[i]);
            if (!(v >= 0.0f && v <= 1.0f)) { ok = 0; break; }
        }
        *flag = ok;
    }
}

// ---------------- fill ----------------
__global__ void k_fill(float* accb, float* nden, unsigned* nmax) {
    int tid = blockIdx.x * 256 + threadIdx.x;
    if (tid < NNODES * 1600) accb[tid] = 0.0f;
    if (tid < NNODES * 8) { nden[tid] = 0.0f; nmax[tid] = ENC_NEGINF; }
}

// ---------------- alpha prepass: EPB=4, shared weights ----------------
template<bool BF>
__global__ __launch_bounds__(256, 3) void k_alpha(
    const void* __restrict__ node_feats, const void* __restrict__ edge_dist,
    const void* __restrict__ wigner, const void* __restrict__ emb_s,
    const void* __restrict__ emb_r,
    const void* __restrict__ rw1, const void* __restrict__ rb1,
    const void* __restrict__ rl1s, const void* __restrict__ rl1b,
    const void* __restrict__ rw2, const void* __restrict__ rb2,
    const void* __restrict__ rl2s, const void* __restrict__ rl2b,
    const void* __restrict__ rw3, const void* __restrict__ rb3,
    const void* __restrict__ c1w0, const void* __restrict__ c1b0,
    const void* __restrict__ an_s, const void* __restrict__ an_b,
    const void* __restrict__ adot,
    const int* __restrict__ species, const int* __restrict__ senders,
    const int* __restrict__ receivers, const int* __restrict__ dtf,
    float* __restrict__ alpha_out, unsigned* __restrict__ nmax)
{
    if ((*dtf != 0) != BF) return;
    __shared__ __align__(16) float sm[12160];
    float* XE   = sm;
    float* T1   = sm + 768;
    float* H1   = sm + 1024;
    float* T2   = sm + 1280;
    float* H2   = sm + 1536;
    float* rad0 = sm + 1792;
    float* x0   = sm + 4352;
    float* R    = sm + 6912;
    float* extraA = sm + 11136;

    const int t = threadIdx.x;
    const int e0 = blockIdx.x * EPB;
    const int eg = t >> 6, tt = t & 63;

    {
        int ee = e0 + eg;
        XE[eg * 192 + tt]       = LD1<BF>(edge_dist, (size_t)ee * 64 + tt);
        XE[eg * 192 + 64 + tt]  = LD1<BF>(emb_s, (size_t)species[senders[ee]] * 64 + tt);
        XE[eg * 192 + 128 + tt] = LD1<BF>(emb_r, (size_t)species[receivers[ee]] * 64 + tt);
    }
    __syncthreads();
    {
        float a = LD1<BF>(rb1, tt);
        #pragma unroll 4
        for (int k = 0; k < 192; k++) a += XE[eg * 192 + k] * LD1<BF>(rw1, k * 64 + tt);
        T1[eg * 64 + tt] = a;
    }
    __syncthreads();
    {
        float mu = 0.f;
        for (int k = 0; k < 64; k++) mu += T1[eg * 64 + k];
        mu *= (1.f / 64.f);
        float var = 0.f;
        for (int k = 0; k < 64; k++) { float d = T1[eg * 64 + k] - mu; var += d * d; }
        float xn = (T1[eg * 64 + tt] - mu) * rsqrtf(var * (1.f / 64.f) + 1e-6f) * LD1<BF>(rl1s, tt) + LD1<BF>(rl1b, tt);
        H1[eg * 64 + tt] = xn * sigmf(xn);
    }
    __syncthreads();
    {
        float a = LD1<BF>(rb2, tt);
        #pragma unroll 4
        for (int k = 0; k < 64; k++) a += H1[eg * 64 + k] * LD1<BF>(rw2, k * 64 + tt);
        T2[eg * 64 + tt] = a;
    }
    __syncthreads();
    {
        float mu = 0.f;
        for (int k = 0; k < 64; k++) mu += T2[eg * 64 + k];
        mu *= (1.f / 64.f);
        float var = 0.f;
        for (int k = 0; k < 64; k++) { float d = T2[eg * 64 + k] - mu; var += d * d; }
        float xn = (T2[eg * 64 + tt] - mu) * rsqrtf(var * (1.f / 64.f) + 1e-6f) * LD1<BF>(rl2s, tt) + LD1<BF>(rl2b, tt);
        H2[eg * 64 + tt] = xn * sigmf(xn);
    }
    __syncthreads();
    if (t < 160) {
        int j0 = t * 4;
        float4 acc[EPB];
        float4 bv = LD4<BF>(rb3, j0);
        #pragma unroll
        for (int e = 0; e < EPB; e++) acc[e] = bv;
        PSTREAM_1(rw3, 1536, j0, (H2 + e * 64), 0, 64, EPB)
        #pragma unroll
        for (int e = 0; e < EPB; e++) *(float4*)&rad0[e * 640 + j0] = acc[e];
    }
    __syncthreads();
    {
        float* X  = R;
        float* WG = R + 3200;
        for (int e = 0; e < EPB; e++) {
            int s_ = senders[e0 + e], r_ = receivers[e0 + e];
            for (int q = t; q < 800; q += 256) {
                int k = q >> 5, c0 = (q & 31) * 4;
                float4 v = (c0 < 64) ? LD4<BF>(node_feats, (size_t)s_ * 1600 + k * 64 + c0)
                                     : LD4<BF>(node_feats, (size_t)r_ * 1600 + k * 64 + (c0 - 64));
                *(float4*)&X[q * 4] = v;
            }
            for (int i = t; i < 125; i += 256) WG[i] = LD1<BF>(wigner, (size_t)(e0 + e) * 475 + i);
            __syncthreads();
            if (t < 160) {
                int m = t >> 5, c0 = (t & 31) * 4;
                float4 acc = make_float4(0.f, 0.f, 0.f, 0.f);
                #pragma unroll
                for (int k = 0; k < 25; k++) fma4(acc, WG[m * 25 + k], *(const float4*)&X[k * 128 + c0]);
                float4 rv = *(const float4*)&rad0[e * 640 + t * 4];
                acc.x *= rv.x; acc.y *= rv.y; acc.z *= rv.z; acc.w *= rv.w;
                *(float4*)&x0[e * 640 + t * 4] = acc;
            }
            __syncthreads();
        }
    }
    {
        float* Y = R;
        int col = t & 63, kq = t >> 6;
        int j0 = 320 + col * 4;
        int ibase = kq * 160;
        float4 acc[EPB];
        #pragma unroll
        for (int e = 0; e < EPB; e++) acc[e] = make_float4(0.f, 0.f, 0.f, 0.f);
        PSTREAM_1(c1w0, 640, j0, (x0 + e * 640), ibase, 160, EPB)
        __syncthreads();
        #pragma unroll
        for (int e = 0; e < EPB; e++) *(float4*)&Y[(e * 256 + kq * 64 + col) * 4] = acc[e];
        __syncthreads();
        {
            int e = t >> 6, c = t & 63;
            float4 s = LD4<BF>(c1b0, 320 + c * 4);
            #pragma unroll
            for (int q = 0; q < 4; q++) {
                float4 v = *(const float4*)&Y[(e * 256 + q * 64 + c) * 4];
                s.x += v.x; s.y += v.y; s.z += v.z; s.w += v.w;
            }
            *(float4*)&extraA[e * 256 + c * 4] = s;
        }
    }
    __syncthreads();
    if (t < 32) {
        int e = t >> 3, h = t & 7;
        float mu = 0.0f;
        for (int k = 0; k < 32; k++) mu += extraA[e * 256 + h * 32 + k];
        mu *= (1.0f / 32.0f);
        float var = 0.0f;
        for (int k = 0; k < 32; k++) { float d = extraA[e * 256 + h * 32 + k] - mu; var += d * d; }
        float rs = rsqrtf(var * (1.0f / 32.0f) + 1e-6f);
        float logit = 0.0f;
        for (int k = 0; k < 32; k++) {
            float xn = (extraA[e * 256 + h * 32 + k] - mu) * rs * LD1<BF>(an_s, k) + LD1<BF>(an_b, k);
            float slr = 0.6f * xn + 0.4f * xn * (2.0f * sigmf(xn) - 1.0f);
            logit += slr * LD1<BF>(adot, h * 32 + k);
        }
        int r = receivers[e0 + e];
        alpha_out[(size_t)(e0 + e) * 8 + h] = logit;
        atomicMax(&nmax[r * 8 + h], encF(logit));
    }
}

// ---------------- exp + denom ----------------
__global__ void k_exp(const int* __restrict__ receivers, const unsigned* __restrict__ nmax,
                      float* __restrict__ alpha, float* __restrict__ nden) {
    int tid = blockIdx.x * 256 + threadIdx.x;
    if (tid >= EDGES * 8) return;
    int e = tid >> 3, h = tid & 7;
    int r = receivers[e];
    float m = decF(nmax[r * 8 + h]);
    float ex = expf(alpha[tid] - m);
    alpha[tid] = ex;
    atomicAdd(&nden[r * 8 + h], ex);
}

// ---------------- mega2: 4 edges per block, 512 threads ----------------
// LDS map: identical to r6 (verified). 78976 B -> 2 blocks/CU = 16 waves/CU
// = exactly 4 waves/SIMD. waves_per_eu(4,4) pins the allocator to that tier
// (r7 lesson: with min-only bounds it squeezed to 64 VGPR chasing an
// LDS-unreachable 8-wave tier and spilled the double-buffer to scratch).
template<bool BF>
__global__ __launch_bounds__(512) __attribute__((amdgpu_waves_per_eu(4, 4))) void k_mega2(
    const void* __restrict__ node_feats, const void* __restrict__ edge_dist,
    const void* __restrict__ wigner, const void* __restrict__ wigner_inv,
    const void* __restrict__ to_grid, const void* __restrict__ from_grid,
    const void* __restrict__ emb_s, const void* __restrict__ emb_r,
    const void* __restrict__ rw1, const void* __restrict__ rb1,
    const void* __restrict__ rl1s, const void* __restrict__ rl1b,
    const void* __restrict__ rw2, const void* __restrict__ rb2,
    const void* __restrict__ rl2s, const void* __restrict__ rl2b,
    const void* __restrict__ rw3, const void* __restrict__ rb3,
    const void* __restrict__ c1w0, const void* __restrict__ c1b0,
    const void* __restrict__ c1w1, const void* __restrict__ c1w2,
    const void* __restrict__ c2w0, const void* __restrict__ c2b0,
    const void* __restrict__ c2w1, const void* __restrict__ c2w2,
    const void* __restrict__ proj_w,
    const int* __restrict__ species, const int* __restrict__ senders,
    const int* __restrict__ receivers, const int* __restrict__ dtf,
    const float* __restrict__ alpha, const float* __restrict__ nden,
    float* __restrict__ accb)
{
    if ((*dtf != 0) != BF) return;
    __shared__ __align__(16) float sm[19744];
    float* Q   = sm;
    float* C   = sm + 9728;
    float* RAD = sm + 13408;
    float* YF  = sm + 14592;
    float* GAT = sm + 19456;
    float* ALs = sm + 19712;

    const int t = threadIdx.x;
    const int e0 = blockIdx.x * EPB;
    int rcv[EPB];
    #pragma unroll
    for (int e = 0; e < EPB; e++) rcv[e] = receivers[e0 + e];

    // ---- P1: radial MLP ----
    {
        float* XE = C;
        float* T1 = C + 768;
        float* H1 = C + 1024;
        float* T2 = C + 1280;
        float* H2 = C + 1536;
        for (int i = t; i < 768; i += 512) {
            int e = i / 192, j = i - e * 192;
            int ee = e0 + e;
            float v;
            if (j < 64)       v = LD1<BF>(edge_dist, (size_t)ee * 64 + j);
            else if (j < 128) v = LD1<BF>(emb_s, (size_t)species[senders[ee]] * 64 + (j - 64));
            else              v = LD1<BF>(emb_r, (size_t)species[receivers[ee]] * 64 + (j - 128));
            XE[e * 192 + j] = v;
        }
        __syncthreads();
        const int eg = t >> 6, tt = t & 63;
        if (t < 256) {
            float a = LD1<BF>(rb1, tt);
            #pragma unroll 4
            for (int k = 0; k < 192; k++) a += XE[eg * 192 + k] * LD1<BF>(rw1, k * 64 + tt);
            T1[eg * 64 + tt] = a;
        }
        __syncthreads();
        if (t < 256) {
            float mu = 0.f;
            for (int k = 0; k < 64; k++) mu += T1[eg * 64 + k];
            mu *= (1.f / 64.f);
            float var = 0.f;
            for (int k = 0; k < 64; k++) { float d = T1[eg * 64 + k] - mu; var += d * d; }
            float xn = (T1[eg * 64 + tt] - mu) * rsqrtf(var * (1.f / 64.f) + 1e-6f) * LD1<BF>(rl1s, tt) + LD1<BF>(rl1b, tt);
            H1[eg * 64 + tt] = xn * sigmf(xn);
        }
        __syncthreads();
        if (t < 256) {
            float a = LD1<BF>(rb2, tt);
            #pragma unroll 4
            for (int k = 0; k < 64; k++) a += H1[eg * 64 + k] * LD1<BF>(rw2, k * 64 + tt);
            T2[eg * 64 + tt] = a;
        }
        __syncthreads();
        if (t < 256) {
            float mu = 0.f;
            for (int k = 0; k < 64; k++) mu += T2[eg * 64 + k];
            mu *= (1.f / 64.f);
            float var = 0.f;
            for (int k = 0; k < 64; k++) { float d = T2[eg * 64 + k] - mu; var += d * d; }
            float xn = (T2[eg * 64 + tt] - mu) * rsqrtf(var * (1.f / 64.f) + 1e-6f) * LD1<BF>(rl2s, tt) + LD1<BF>(rl2b, tt);
            H2[eg * 64 + tt] = xn * sigmf(xn);
        }
        __syncthreads();
        if (t < 384) {
            int j0 = t * 4;
            float4 acc[EPB];
            float4 bv = LD4<BF>(rb3, j0);
            #pragma unroll
            for (int e = 0; e < EPB; e++) acc[e] = bv;
            PSTREAM_1(rw3, 1536, j0, (H2 + e * 64), 0, 64, EPB)
            #pragma unroll
            for (int e = 0; e < EPB; e++) *(float4*)&RAD[e * 1536 + j0] = acc[e];
        }
        __syncthreads();
    }

    // ---- P2: gather + wigner rotate + rad scale (per edge sequential) ----
    {
        float* X  = C;          // 3200
        float* WG = C + 3200;   // 480
        for (int e = 0; e < EPB; e++) {
            int s_ = senders[e0 + e], r_ = receivers[e0 + e];
            for (int q = t; q < 800; q += 512) {
                int k = q >> 5, c0 = (q & 31) * 4;
                float4 v = (c0 < 64) ? LD4<BF>(node_feats, (size_t)s_ * 1600 + k * 64 + c0)
                                     : LD4<BF>(node_feats, (size_t)r_ * 1600 + k * 64 + (c0 - 64));
                *(float4*)&X[q * 4] = v;
            }
            if (t < 475) WG[t] = LD1<BF>(wigner, (size_t)(e0 + e) * 475 + t);
            __syncthreads();
            for (int q = t; q < 608; q += 512) {
                int m = q >> 5, c0 = (q & 31) * 4;
                float4 acc = make_float4(0.f, 0.f, 0.f, 0.f);
                #pragma unroll
                for (int k = 0; k < 25; k++) fma4(acc, WG[m * 25 + k], *(const float4*)&X[k * 128 + c0]);
                int ri0;
                if (m < 5)       ri0 = m * 128 + c0;
                else if (m < 13) ri0 = 640 + ((m - 5) & 3) * 128 + c0;
                else             ri0 = 1152 + ((m - 13) % 3) * 128 + c0;
                float4 rv = *(const float4*)&RAD[e * 1536 + ri0];
                acc.x *= rv.x; acc.y *= rv.y; acc.z *= rv.z; acc.w *= rv.w;
                *(float4*)&Q[e * 2432 + q * 4] = acc;
            }
            __syncthreads();
        }
    }

    float4 ra[EPB], rb[EPB];

    // ---- P3: conv1 (512-thread schedule) ----
    {
        float* EF2 = C;
        float* YM  = YF;  // m1 staging [e][r][512] = 4096 floats
        // stage A: m1 with (row, colgroup, k-half) = 2x128x2 = 512 threads
        {
            int cg = t & 127, r = (t >> 7) & 1, kh = t >> 8;
            int j0 = cg * 4;
            float4 acc[EPB];
            #pragma unroll
            for (int e = 0; e < EPB; e++) acc[e] = make_float4(0.f, 0.f, 0.f, 0.f);
            int kb0 = 256 * kh;
            PSTREAM_1(c1w1, 512, j0, (Q + e * 2432 + 640 + 512 * r), kb0, 256, EPB)
            if (kh == 1) {
                #pragma unroll
                for (int e = 0; e < EPB; e++) *(float4*)&YM[(e * 2 + r) * 512 + j0] = acc[e];
            }
            __syncthreads();
            if (kh == 0) {
                #pragma unroll
                for (int e = 0; e < EPB; e++) {
                    float4 p = *(const float4*)&YM[(e * 2 + r) * 512 + j0];
                    acc[e].x += p.x; acc[e].y += p.y; acc[e].z += p.z; acc[e].w += p.w;
                    *(float4*)&YM[(e * 2 + r) * 512 + j0] = acc[e];
                }
            }
            __syncthreads();
            for (int u = t; u < 1024; u += 512) {
                int e = u >> 8, j = u & 255;
                float y0l = YM[(e * 2 + 0) * 512 + j];
                float y0u = YM[(e * 2 + 0) * 512 + 256 + j];
                float y1l = YM[(e * 2 + 1) * 512 + j];
                float y1u = YM[(e * 2 + 1) * 512 + 256 + j];
                EF2[e * 1216 + 320 + j] = y0l - y1u;
                EF2[e * 1216 + 576 + j] = y1l + y0u;
            }
            __syncthreads();
        }
        // stage B: m0 k-split (2 kh x 96 jq = 192 thr) || m2 single-row (192 thr)
        // NOTE: m0 has exactly 96 output f4-groups: 80 -> EF2[0,320), 16 -> GAT
        {
            float* MS  = YF;          // m0 kh=1 partials [e][96] f4 = 1536
            float* M2S = YF + 1536;   // m2 upper stage [e][r][48] f4 = 1536
            float4 keep[EPB];
            #pragma unroll
            for (int e = 0; e < EPB; e++) keep[e] = make_float4(0.f, 0.f, 0.f, 0.f);
            if (t < 192) {
                int kh = (t >= 96) ? 1 : 0;
                int jq = t - 96 * kh;  // 0..95
                int cmj = (jq < 80) ? jq * 4 : 576 + (jq - 80) * 4;
                float4 acc[EPB];
                #pragma unroll
                for (int e = 0; e < EPB; e++) acc[e] = make_float4(0.f, 0.f, 0.f, 0.f);
                int kb0 = kh * 320;
                PSTREAM_1(c1w0, 640, cmj, (Q + e * 2432), kb0, 320, EPB)
                if (kh) {
                    #pragma unroll
                    for (int e = 0; e < EPB; e++) *(float4*)&MS[(e * 96 + jq) * 4] = acc[e];
                } else {
                    #pragma unroll
                    for (int e = 0; e < EPB; e++) keep[e] = acc[e];
                }
            } else if (t < 384) {
                int u = t - 192;
                int r = (u >= 96) ? 1 : 0, cg = u - 96 * r;  // 0..95
                int j0 = cg * 4;
                float4 acc[EPB];
                #pragma unroll
                for (int e = 0; e < EPB; e++) acc[e] = make_float4(0.f, 0.f, 0.f, 0.f);
                int abase = 1664 + 384 * r;
                PSTREAM_1(c1w2, 384, j0, (Q + e * 2432 + abase), 0, 384, EPB)
                if (cg >= 48) {
                    #pragma unroll
                    for (int e = 0; e < EPB; e++)
                        *(float4*)&M2S[((e * 2 + r) * 48 + (cg - 48)) * 4] = acc[e];
                } else {
                    #pragma unroll
                    for (int e = 0; e < EPB; e++) keep[e] = acc[e];
                }
            }
            __syncthreads();
            if (t < 96) {  // m0 combine (kh=0 threads)
                int jq = t;
                int cmj = (jq < 80) ? jq * 4 : 576 + (jq - 80) * 4;
                float4 bv = LD4<BF>(c1b0, cmj);
                #pragma unroll
                for (int e = 0; e < EPB; e++) {
                    float4 p = *(const float4*)&MS[(e * 96 + jq) * 4];
                    float4 v;
                    v.x = keep[e].x + p.x + bv.x; v.y = keep[e].y + p.y + bv.y;
                    v.z = keep[e].z + p.z + bv.z; v.w = keep[e].w + p.w + bv.w;
                    if (jq < 80) *(float4*)&EF2[e * 1216 + jq * 4] = v;
                    else         *(float4*)&GAT[e * 64 + (jq - 80) * 4] = v;
                }
            } else if (t >= 192 && t < 384) {  // m2 combine (cg < 48)
                int u = t - 192;
                int r = (u >= 96) ? 1 : 0, cg = u - 96 * r;
                if (cg < 48) {
                    int j0 = cg * 4;
                    #pragma unroll
                    for (int e = 0; e < EPB; e++) {
                        float4 o = *(const float4*)&M2S[((e * 2 + (1 - r)) * 48 + cg) * 4];
                        float4 v;
                        if (r == 0) {
                            v.x = keep[e].x - o.x; v.y = keep[e].y - o.y;
                            v.z = keep[e].z - o.z; v.w = keep[e].w - o.w;
                            *(float4*)&EF2[e * 1216 + 832 + j0] = v;
                        } else {
                            v.x = keep[e].x + o.x; v.y = keep[e].y + o.y;
                            v.z = keep[e].z + o.z; v.w = keep[e].w + o.w;
                            *(float4*)&EF2[e * 1216 + 1024 + j0] = v;
                        }
                    }
                }
            }
            __syncthreads();
        }
    }

    // ---- P4: grid nonlinearity (per edge, 512-wide) ----
    {
        float* FE  = YF;        // FEATS [e][1216]
        float* G   = Q;         // 100 x 64 = 6400
        float* S2  = Q + 6400;  // 608 f4 = 2432
        float* EF2 = C;
        for (int e = 0; e < EPB; e++) {
            for (int idx = t; idx < 1600; idx += 512) {
                int gi = idx >> 4, c0 = (idx & 15) * 4;
                float4 acc = make_float4(0.f, 0.f, 0.f, 0.f);
                #pragma unroll
                for (int m = 0; m < 19; m++)
                    fma4(acc, LD1<BF>(to_grid, gi * 19 + m),
                         *(const float4*)&EF2[e * 1216 + m * 64 + c0]);
                silu4(acc);
                *(float4*)&G[gi * 64 + c0] = acc;
            }
            __syncthreads();
            for (int idx = t; idx < 608; idx += 512) {
                int m = idx >> 5, cq = (idx >> 1) & 15, h = idx & 1, c0 = cq * 4;
                int g0 = h * 50;
                float4 acc = make_float4(0.f, 0.f, 0.f, 0.f);
                #pragma unroll 5
                for (int gi = 0; gi < 50; gi++)
                    fma4(acc, LD1<BF>(from_grid, (g0 + gi) * 19 + m),
                         *(const float4*)&G[(g0 + gi) * 64 + c0]);
                *(float4*)&S2[idx * 4] = acc;
            }
            __syncthreads();
            if (t < 304) {
                int m = t >> 4, cq = t & 15;
                int pb = (m * 32 + cq * 2) * 4;
                float4 a = *(const float4*)&S2[pb];
                float4 b = *(const float4*)&S2[pb + 4];
                a.x += b.x; a.y += b.y; a.z += b.z; a.w += b.w;
                *(float4*)&FE[e * 1216 + m * 64 + cq * 4] = a;
            }
            __syncthreads();
        }
        if (t < 64) {
            #pragma unroll
            for (int e = 0; e < EPB; e++) { float x = GAT[e * 64 + t]; FE[e * 1216 + t] = x * sigmf(x); }
        }
        __syncthreads();
    }

    // ---- P5: conv2 -> EF3 in Q (512-thread schedule) ----
    {
        float* FE  = YF;
        float* M1S = C;   // m1 upper stage [e][r][128] f4 = 4096
        float4 keep[EPB];
        {
            int cg = t & 255, r = t >> 8;
            int j0 = cg * 4;
            float4 acc[EPB];
            #pragma unroll
            for (int e = 0; e < EPB; e++) acc[e] = make_float4(0.f, 0.f, 0.f, 0.f);
            int abase = 320 + 256 * r;
            PSTREAM_1(c2w1, 1024, j0, (FE + e * 1216 + abase), 0, 256, EPB)
            if (cg >= 128) {
                #pragma unroll
                for (int e = 0; e < EPB; e++)
                    *(float4*)&M1S[((e * 2 + r) * 128 + (cg - 128)) * 4] = acc[e];
            } else {
                #pragma unroll
                for (int e = 0; e < EPB; e++) keep[e] = acc[e];
            }
            __syncthreads();
            if (cg < 128) {
                #pragma unroll
                for (int e = 0; e < EPB; e++) {
                    float4 o = *(const float4*)&M1S[((e * 2 + (1 - r)) * 128 + cg) * 4];
                    float4 v;
                    if (r == 0) {
                        v.x = keep[e].x - o.x; v.y = keep[e].y - o.y;
                        v.z = keep[e].z - o.z; v.w = keep[e].w - o.w;
                        *(float4*)&Q[e * 2432 + 640 + j0] = v;
                    } else {
                        v.x = keep[e].x + o.x; v.y = keep[e].y + o.y;
                        v.z = keep[e].z + o.z; v.w = keep[e].w + o.w;
                        *(float4*)&Q[e * 2432 + 1152 + j0] = v;
                    }
                }
            }
            __syncthreads();
        }
        // stage B: m0 (t<160 full-k) || m2 both-rows (160<=t<352)
        {
            float* M2S = C;  // m2 upper stage [e][r][96] f4 = 3072
            if (t < 160) {
                int j0 = t * 4;
                float4 acc[EPB];
                float4 bv = LD4<BF>(c2b0, j0);
                #pragma unroll
                for (int e = 0; e < EPB; e++) acc[e] = bv;
                PSTREAM_1(c2w0, 640, j0, (FE + e * 1216), 0, 320, EPB)
                #pragma unroll
                for (int e = 0; e < EPB; e++) *(float4*)&Q[e * 2432 + j0] = acc[e];
            } else if (t < 352) {
                int cg = t - 160;  // 0..191
                int j0 = cg * 4;
                #pragma unroll
                for (int e = 0; e < EPB; e++) { ra[e] = make_float4(0,0,0,0); rb[e] = make_float4(0,0,0,0); }
                PSTREAM_2(c2w2, 768, j0, (FE + e * 1216 + 832), (FE + e * 1216 + 1024), 192)
                if (cg >= 96) {
                    #pragma unroll
                    for (int e = 0; e < EPB; e++) {
                        *(float4*)&M2S[((e * 2 + 0) * 96 + (cg - 96)) * 4] = ra[e];
                        *(float4*)&M2S[((e * 2 + 1) * 96 + (cg - 96)) * 4] = rb[e];
                    }
                }
            }
            __syncthreads();
            if (t >= 160 && t < 256) {
                int cg = t - 160;  // 0..95
                int j0 = cg * 4;
                #pragma unroll
                for (int e = 0; e < EPB; e++) {
                    float4 y1u = *(const float4*)&M2S[((e * 2 + 1) * 96 + cg) * 4];
                    float4 y0u = *(const float4*)&M2S[((e * 2 + 0) * 96 + cg) * 4];
                    float4 r, im;
                    r.x = ra[e].x - y1u.x; r.y = ra[e].y - y1u.y;
                    r.z = ra[e].z - y1u.z; r.w = ra[e].w - y1u.w;
                    im.x = rb[e].x + y0u.x; im.y = rb[e].y + y0u.y;
                    im.z = rb[e].z + y0u.z; im.w = rb[e].w + y0u.w;
                    *(float4*)&Q[e * 2432 + 1664 + j0] = r;
                    *(float4*)&Q[e * 2432 + 2048 + j0] = im;
                }
            }
            __syncthreads();
        }
    }

    // ---- P7: wigner_inv rotate + alpha + fused proj (edge-split proj) ----
    {
        float* WV = C;           // [e][480]
        float* EO = C + 1920;    // up to 13*512 = 6656 floats
        if (t < 32) {
            int h = t & 7;
            int ee = e0 + (t >> 3);
            ALs[t] = alpha[(size_t)ee * 8 + h] / (nden[(size_t)receivers[ee] * 8 + h] + 1e-16f);
        }
        for (int i = t; i < 1900; i += 512) {
            int e = i / 475, j = i - e * 475;
            WV[e * 480 + j] = LD1<BF>(wigner_inv, (size_t)(e0 + e) * 475 + j);
        }
        __syncthreads();
        for (int kb = 0; kb < 25; kb += 13) {
            const int nk = (kb == 0) ? 13 : 12;
            for (int u = t; u < nk * 128; u += 512) {
                int e = u & 3, idx = u >> 2;
                int ki = idx >> 5, c0 = (idx & 31) * 4;
                int k = kb + ki;
                float4 acc = make_float4(0.f, 0.f, 0.f, 0.f);
                #pragma unroll
                for (int m = 0; m < 19; m++)
                    fma4(acc, WV[e * 480 + k * 19 + m], *(const float4*)&Q[e * 2432 + m * 128 + c0]);
                float al = ALs[e * 8 + (c0 >> 4)];
                int b = (ki * 128 + c0) * 4 + e;
                EO[b + 0]  = acc.x * al;
                EO[b + 4]  = acc.y * al;
                EO[b + 8]  = acc.z * al;
                EO[b + 12] = acc.w * al;
            }
            __syncthreads();
            if (t < nk * 32) {
                int ki = t >> 5;
                int rem = t & 31;
                int o = rem >> 1, eh = rem & 1;
                int o0 = o * 4;
                int k = kb + ki;
                int l = (k == 0) ? 0 : (k < 4) ? 1 : (k < 9) ? 2 : (k < 16) ? 3 : 4;
                float4 pa0 = make_float4(0,0,0,0), pa1 = pa0;
                const float* eob = &EO[ki * 512 + eh * 2];
                size_t base = (size_t)l * 8192 + o0;
                // prefetched proj_w stream (double-buffered)
                float4 qA0, qA1, qA2, qA3, qB0, qB1, qB2, qB3;
                qA0 = LD4<BF>(proj_w, base + (size_t)0 * 64);
                qA1 = LD4<BF>(proj_w, base + (size_t)1 * 64);
                qA2 = LD4<BF>(proj_w, base + (size_t)2 * 64);
                qA3 = LD4<BF>(proj_w, base + (size_t)3 * 64);
                int c = 0;
                #define PROJ_FMA(PD, cc) \
                    fma4(pa0, eob[((cc) + 0) * 4], PD##0); fma4(pa1, eob[((cc) + 0) * 4 + 1], PD##0); \
                    fma4(pa0, eob[((cc) + 1) * 4], PD##1); fma4(pa1, eob[((cc) + 1) * 4 + 1], PD##1); \
                    fma4(pa0, eob[((cc) + 2) * 4], PD##2); fma4(pa1, eob[((cc) + 2) * 4 + 1], PD##2); \
                    fma4(pa0, eob[((cc) + 3) * 4], PD##3); fma4(pa1, eob[((cc) + 3) * 4 + 1], PD##3);
                for (; c + 8 < 128; c += 8) {
                    qB0 = LD4<BF>(proj_w, base + (size_t)(c + 4) * 64);
                    qB1 = LD4<BF>(proj_w, base + (size_t)(c + 5) * 64);
                    qB2 = LD4<BF>(proj_w, base + (size_t)(c + 6) * 64);
                    qB3 = LD4<BF>(proj_w, base + (size_t)(c + 7) * 64);
                    PROJ_FMA(qA, c)
                    qA0 = LD4<BF>(proj_w, base + (size_t)(c + 8) * 64);
                    qA1 = LD4<BF>(proj_w, base + (size_t)(c + 9) * 64);
                    qA2 = LD4<BF>(proj_w, base + (size_t)(c + 10) * 64);
                    qA3 = LD4<BF>(proj_w, base + (size_t)(c + 11) * 64);
                    PROJ_FMA(qB, (c + 4))
                }
                qB0 = LD4<BF>(proj_w, base + (size_t)(c + 4) * 64);
                qB1 = LD4<BF>(proj_w, base + (size_t)(c + 5) * 64);
                qB2 = LD4<BF>(proj_w, base + (size_t)(c + 6) * 64);
                qB3 = LD4<BF>(proj_w, base + (size_t)(c + 7) * 64);
                PROJ_FMA(qA, c)
                PROJ_FMA(qB, (c + 4))
                #undef PROJ_FMA
                int ep = eh * 2;
                float* d0 = &accb[(size_t)rcv[ep] * 1600 + k * 64 + o0];
                atomicAdd(d0 + 0, pa0.x); atomicAdd(d0 + 1, pa0.y);
                atomicAdd(d0 + 2, pa0.z); atomicAdd(d0 + 3, pa0.w);
                float* d1 = &accb[(size_t)rcv[ep + 1] * 1600 + k * 64 + o0];
                atomicAdd(d1 + 0, pa1.x); atomicAdd(d1 + 1, pa1.y);
                atomicAdd(d1 + 2, pa1.z); atomicAdd(d1 + 3, pa1.w);
            }
            __syncthreads();
        }
    }
}

// ---------------- bias + convert ----------------
template<bool BF>
__global__ void k_out(const float* __restrict__ accb, const void* __restrict__ proj_b,
                      void* __restrict__ out, const int* __restrict__ dtf) {
    if ((*dtf != 0) != BF) return;
    int i = blockIdx.x * 256 + threadIdx.x;
    if (i >= NNODES * 1600) return;
    int r = i % 1600;
    int m = r >> 6, o = r & 63;
    float v = accb[i] + ((m == 0) ? LD1<BF>(proj_b, o) : 0.0f);
    if (BF) ((bf16*)out)[i] = __float2bfloat16(v);
    else    ((float*)out)[i] = v;
}

extern "C" void kernel_launch(void* const* d_in, const int* in_sizes, int n_in,
                              void* d_out, int out_size, void* d_ws, size_t ws_size,
                              hipStream_t stream) {
    const void* node_feats = d_in[0];
    const void* edge_dist  = d_in[1];
    const void* wigner     = d_in[2];
    const void* wigner_inv = d_in[3];
    const void* to_grid    = d_in[4];
    const void* from_grid  = d_in[5];
    const void* emb_s      = d_in[6];
    const void* emb_r      = d_in[7];
    const void* rw1  = d_in[8];
    const void* rb1  = d_in[9];
    const void* rl1s = d_in[10];
    const void* rl1b = d_in[11];
    const void* rw2  = d_in[12];
    const void* rb2  = d_in[13];
    const void* rl2s = d_in[14];
    const void* rl2b = d_in[15];
    const void* rw3  = d_in[16];
    const void* rb3  = d_in[17];
    const void* c1w0 = d_in[18];
    const void* c1b0 = d_in[19];
    const void* c1w1 = d_in[20];
    const void* c1w2 = d_in[21];
    const void* c2w0 = d_in[22];
    const void* c2b0 = d_in[23];
    const void* c2w1 = d_in[24];
    const void* c2w2 = d_in[25];
    const void* an_s = d_in[26];
    const void* an_b = d_in[27];
    const void* adot = d_in[28];
    const void* proj_w = d_in[29];
    const void* proj_b = d_in[30];
    const int* species   = (const int*)d_in[31];
    const int* senders   = (const int*)d_in[32];
    const int* receivers = (const int*)d_in[33];

    char* ws = (char*)d_ws;
    float*    accb  = (float*)ws;                   // 32,000,000 B
    float*    alpha = (float*)(ws + 32000000);      // 800,000 B
    unsigned* nmax  = (unsigned*)(ws + 32800000);   // 160,000 B
    float*    nden  = (float*)(ws + 32960000);      // 160,000 B
    int*      dtf   = (int*)(ws + 33120000);        // 4 B

    k_detect<<<1, 64, 0, stream>>>(edge_dist, dtf);
    k_fill<<<(NNODES * 1600 + 255) / 256, 256, 0, stream>>>(accb, nden, nmax);

    k_alpha<true><<<NBLK, 256, 0, stream>>>(
        node_feats, edge_dist, wigner, emb_s, emb_r,
        rw1, rb1, rl1s, rl1b, rw2, rb2, rl2s, rl2b, rw3, rb3,
        c1w0, c1b0, an_s, an_b, adot, species, senders, receivers, dtf,
        alpha, nmax);
    k_alpha<false><<<NBLK, 256, 0, stream>>>(
        node_feats, edge_dist, wigner, emb_s, emb_r,
        rw1, rb1, rl1s, rl1b, rw2, rb2, rl2s, rl2b, rw3, rb3,
        c1w0, c1b0, an_s, an_b, adot, species, senders, receivers, dtf,
        alpha, nmax);

    k_exp<<<(EDGES * 8 + 255) / 256, 256, 0, stream>>>(receivers, nmax, alpha, nden);

    k_mega2<true><<<NBLK, 512, 0, stream>>>(
        node_feats, edge_dist, wigner, wigner_inv, to_grid, from_grid, emb_s, emb_r,
        rw1, rb1, rl1s, rl1b, rw2, rb2, rl2s, rl2b, rw3, rb3,
        c1w0, c1b0, c1w1, c1w2, c2w0, c2b0, c2w1, c2w2, proj_w,
        species, senders, receivers, dtf, alpha, nden, accb);
    k_mega2<false><<<NBLK, 512, 0, stream>>>(
        node_feats, edge_dist, wigner, wigner_inv, to_grid, from_grid, emb_s, emb_r,
        rw1, rb1, rl1s, rl1b, rw2, rb2, rl2s, rl2b, rw3, rb3,
        c1w0, c1b0, c1w1, c1w2, c2w0, c2b0, c2w1, c2w2, proj_w,
        species, senders, receivers, dtf, alpha, nden, accb);

    k_out<true><<<(NNODES * 1600 + 255) / 256, 256, 0, stream>>>(accb, proj_b, d_out, dtf);
    k_out<false><<<(NNODES * 1600 + 255) / 256, 256, 0, stream>>>(accb, proj_b, d_out, dtf);
}